// Round 2
// 201.762 us; speedup vs baseline: 1.0113x; 1.0113x over previous
//
#include <hip/hip_runtime.h>

// Tokenizer: masked row compaction, fused single-kernel version.
//   inputs:  hidden_states (B,L,D) fp32, token_mask (B,L) int32 (0/1)
//   outputs: chunked (B,M,D) fp32 left-packed zero-padded, counts (B,) as floats
//
// Every block re-derives the bit-compressed mask for the batch row(s) it
// touches:
//   - 4096 mask elems -> 64 x u64 ballot words in LDS (512 B)
//   - 64-entry exclusive popcount scan (one wave, shfl)
//   - per output row m: binary-search the prefix, select the m-th set bit
// The 16 KB mask row is L2/L3-resident after first touch (128 KB total),
// so the redundant per-block reads are ~free; the separate scan kernel,
// its dependency stall, and the src_idx global round-trip all disappear.

typedef float floatx4 __attribute__((ext_vector_type(4)));   // native vec type:
// __builtin_nontemporal_* rejects HIP_vector_type<float,4>, accepts this.

__global__ __launch_bounds__(256) void fused_pack(
        const floatx4* __restrict__ hidden,
        const int*     __restrict__ mask,
        floatx4*       __restrict__ out,
        float*         __restrict__ counts_out,
        int L, int M, int D4, int nrows, int rpb) {
    __shared__ unsigned long long words[64];   // bit-compressed mask row
    __shared__ int excl[65];                   // exclusive popcount prefix + total

    const int t    = threadIdx.x;
    const int lane = t & 63;
    const int wid  = t >> 6;                   // 0..3

    int r = blockIdx.x * rpb;
    const int r1 = min(nrows, r + rpb);
    if (r >= r1) return;

    while (r < r1) {
        const int b = r / M;
        const int mstart = r - b * M;
        const int mend   = min(r1 - b * M, M);  // rows of this batch owned here

        // ---- compress mask row b into 64 ballot words (wave w: words 16w..16w+15)
        const int* mrow = mask + (size_t)b * L;
        #pragma unroll
        for (int i = 0; i < 16; ++i) {
            const int k = wid * 16 + i;                    // word index 0..63
            const unsigned long long bal = __ballot(mrow[k * 64 + lane] != 0);
            if (lane == 0) words[k] = bal;
        }
        __syncthreads();

        // ---- exclusive scan of per-word popcounts (wave 0 only)
        if (wid == 0) {
            const int pc = __popcll(words[lane]);
            int incl = pc;
            #pragma unroll
            for (int off = 1; off < 64; off <<= 1) {
                const int up = __shfl_up(incl, off, 64);
                if (lane >= off) incl += up;
            }
            excl[lane] = incl - pc;
            if (lane == 63) excl[64] = incl;               // row total
        }
        __syncthreads();

        const int cnt = excl[64];
        if (t == 0) counts_out[b] = (float)cnt;            // same value from every
                                                           // block of this batch

        // ---- copy / zero the rows this block owns in batch b
        for (int m = mstart; m < mend; ++m, ++r) {
            const size_t orow = ((size_t)b * M + m) * D4;
            if (m < cnt) {
                // word holding the (m+1)-th set bit: largest k with excl[k] <= m
                int lo = 0, hi = 63;
                #pragma unroll
                for (int s = 0; s < 6; ++s) {
                    const int mid = (lo + hi + 1) >> 1;
                    if (excl[mid] <= m) lo = mid; else hi = mid - 1;
                }
                unsigned long long w = words[lo];
                const int j = m - excl[lo];                // j-th set bit of w
                for (int q = 0; q < j; ++q) w &= w - 1;
                const int l = lo * 64 + __builtin_ctzll(w);

                const size_t irow = ((size_t)b * L + l) * D4;
                for (int i = t; i < D4; i += 256) {
                    const floatx4 v = __builtin_nontemporal_load(&hidden[irow + i]);
                    __builtin_nontemporal_store(v, &out[orow + i]);
                }
            } else {
                const floatx4 z = (floatx4){0.f, 0.f, 0.f, 0.f};
                for (int i = t; i < D4; i += 256)
                    __builtin_nontemporal_store(z, &out[orow + i]);
            }
        }
        __syncthreads();   // LDS reused for the next batch row (if chunk straddles)
    }
}

// M == 0 fallback: every count is necessarily zero.
__global__ void zero_counts(float* counts_out, int B) {
    if ((int)threadIdx.x < B) counts_out[threadIdx.x] = 0.f;
}

extern "C" void kernel_launch(void* const* d_in, const int* in_sizes, int n_in,
                              void* d_out, int out_size, void* d_ws, size_t ws_size,
                              hipStream_t stream) {
    const int B  = 8;                      // per setup_inputs()
    const int BL = in_sizes[1];            // B*L = 32768
    const int D  = in_sizes[0] / BL;       // 1024
    const int L  = BL / B;                 // 4096
    const int M  = (out_size - B) / (B * D);

    const float* hidden = (const float*)d_in[0];
    const int*   mask   = (const int*)d_in[1];
    float*       out    = (float*)d_out;
    float* counts_out   = out + (size_t)B * M * D;

    if (M == 0) {
        zero_counts<<<1, 64, 0, stream>>>(counts_out, B);
        return;
    }

    const int nrows = B * M;
    const int rpb   = (nrows + 2047) / 2048;      // rows per block, ~9
    const int grid  = (nrows + rpb - 1) / rpb;    // <= 2048 blocks
    fused_pack<<<grid, 256, 0, stream>>>((const floatx4*)hidden, mask,
                                         (floatx4*)out, counts_out,
                                         L, M, D / 4, nrows, rpb);
}